// Round 3
// baseline (671.374 us; speedup 1.0000x reference)
//
#include <hip/hip_runtime.h>
#include <hip/hip_fp16.h>

#define HN 4
#define VDIM 2
#define BDIM 2048
#define C1N 1024
#define C2N 2048
#define NDIM 4096
#define EPSV 1e-7f
#define ITEMP (1.0f/0.05f)
#define KSPLIT 2

typedef float f32x4 __attribute__((ext_vector_type(4)));
typedef _Float16 half8 __attribute__((ext_vector_type(8)));

// async global -> LDS, 16B per lane (m97 pattern; LDS dest linear in lane)
__device__ __forceinline__ void gl16(const void* g, void* l){
    __builtin_amdgcn_global_load_lds(
        (const __attribute__((address_space(1))) unsigned int*)g,
        (__attribute__((address_space(3))) unsigned int*)l, 16, 0, 0);
}

// ---------------- zero init (pj .. Sacc region) ----------------
__global__ void kzero(float* p, int n){
    int i = blockIdx.x * blockDim.x + threadIdx.x;
    if (i < n) p[i] = 0.f;
}

// ---------------- pass 1: row softmax stats (max, 1/sum) ----------------
template<int C>
__global__ __launch_bounds__(256) void kstats(const float* __restrict__ x,
                                              float2* __restrict__ st){
    const int bid = blockIdx.x;            // h*NDIM + n
    const int h = bid >> 12;
    const int n = bid & (NDIM - 1);
    const int v = n >> 11, b = n & (BDIM - 1);
    const float4* row = (const float4*)(x + ((size_t)((v*HN + h)*BDIM + b)) * C);
    const int t = threadIdx.x;
    constexpr int NV = C / 1024;
    float4 a[NV];
    float m = -3.4e38f;
#pragma unroll
    for (int i = 0; i < NV; ++i){
        a[i] = row[t + i*256];
        m = fmaxf(m, fmaxf(fmaxf(a[i].x, a[i].y), fmaxf(a[i].z, a[i].w)));
    }
    __shared__ float red[4];
    for (int o = 32; o > 0; o >>= 1) m = fmaxf(m, __shfl_xor(m, o));
    if ((t & 63) == 0) red[t >> 6] = m;
    __syncthreads();
    m = fmaxf(fmaxf(red[0], red[1]), fmaxf(red[2], red[3]));
    __syncthreads();
    float s = 0.f;
#pragma unroll
    for (int i = 0; i < NV; ++i){
        s += expf((a[i].x - m)*ITEMP) + expf((a[i].y - m)*ITEMP)
           + expf((a[i].z - m)*ITEMP) + expf((a[i].w - m)*ITEMP);
    }
    for (int o = 32; o > 0; o >>= 1) s += __shfl_xor(s, o);
    if ((t & 63) == 0) red[t >> 6] = s;
    __syncthreads();
    if (t == 0){
        float tot = red[0] + red[1] + red[2] + red[3];
        st[bid] = make_float2(m, 1.f / tot);
    }
}

// ---- pass 2: normalize + fp16 (hi[,lo]) + transpose to (h,C,N) + exact colsum ----
template<int C, bool LO>
__global__ __launch_bounds__(256) void knt(const float* __restrict__ x,
                                           const float2* __restrict__ st,
                                           unsigned short* __restrict__ thi,
                                           unsigned short* __restrict__ tlo,
                                           float* __restrict__ psum){
    __shared__ unsigned short sh[64][68];
    __shared__ unsigned short sl[64][68];
    __shared__ float2 sst[64];
    const int tid = threadIdx.x;
    const int h  = blockIdx.z;
    const int c0 = blockIdx.x * 64;   // over C
    const int r0 = blockIdx.y * 64;   // over N
    if (tid < 64) sst[tid] = st[h*NDIM + r0 + tid];
    __syncthreads();
    const int col = (tid & 15) * 4;
    float csum[4] = {0.f, 0.f, 0.f, 0.f};
#pragma unroll
    for (int i = 0; i < 4; ++i){
        const int rr = (tid >> 4) + i*16;
        const int n = r0 + rr;
        const int v = n >> 11, b = n & (BDIM - 1);
        float4 xv = *(const float4*)(x + ((size_t)((v*HN + h)*BDIM + b))*C + c0 + col);
        const float m = sst[rr].x, inv = sst[rr].y;
        float vals[4] = {xv.x, xv.y, xv.z, xv.w};
#pragma unroll
        for (int e = 0; e < 4; ++e){
            float val = expf((vals[e] - m)*ITEMP) * inv;
            csum[e] += val;
            __half hh = __float2half_rn(val);
            sh[rr][col + e] = __half_as_ushort(hh);
            if (LO){
                float lo = val - __half2float(hh);
                sl[rr][col + e] = __half_as_ushort(__float2half_rn(lo));
            }
        }
    }
    // exact fp32 column sums: lanes {l, l+16, l+32, l+48} share a column
#pragma unroll
    for (int e = 0; e < 4; ++e){
        csum[e] += __shfl_xor(csum[e], 16);
        csum[e] += __shfl_xor(csum[e], 32);
    }
    if ((tid & 63) < 16){
#pragma unroll
        for (int e = 0; e < 4; ++e)
            atomicAdd(&psum[h*C + c0 + col + e], csum[e]);
    }
    __syncthreads();
    const int rb = (tid & 15) * 4;
#pragma unroll
    for (int i = 0; i < 4; ++i){
        const int cc = (tid >> 4) + i*16;
        ushort4 vh;
        vh.x = sh[rb+0][cc]; vh.y = sh[rb+1][cc]; vh.z = sh[rb+2][cc]; vh.w = sh[rb+3][cc];
        size_t o = ((size_t)(h*C + c0 + cc))*NDIM + r0 + rb;
        *(ushort4*)(thi + o) = vh;
        if (LO){
            ushort4 vl;
            vl.x = sl[rb+0][cc]; vl.y = sl[rb+1][cc]; vl.z = sl[rb+2][cc]; vl.w = sl[rb+3][cc];
            *(ushort4*)(tlo + o) = vl;
        }
    }
}

// ---------------- merged: log(p_seen) table + p_unseen entropy ----------------
__global__ __launch_bounds__(256) void kls(const float* __restrict__ psum_s,
                                           const float* __restrict__ psum_u,
                                           float* __restrict__ lps, float* S){
    int i = blockIdx.x * 256 + threadIdx.x;
    if (i < HN*C1N) lps[i] = logf(fmaxf(psum_s[i] * (1.f/NDIM), EPSV));
    float t = 0.f;
    if (i < HN*C2N){
        float pu = fmaxf(psum_u[i] * (1.f/NDIM), EPSV);
        t = pu * logf(pu);
    }
    for (int o = 32; o > 0; o >>= 1) t += __shfl_xor(t, o);
    __shared__ float red[4];
    if ((threadIdx.x & 63) == 0) red[threadIdx.x >> 6] = t;
    __syncthreads();
    if (threadIdx.x == 0) atomicAdd(&S[1], red[0]+red[1]+red[2]+red[3]);
}

// ------ GEMM (m97 structure, split-fp16 2-MFMA):
// pj[h][c][k] += sum_n xu[h][n][c]*xs[h][n][k]
// A = xu_h16 (h,C2,N) K-contig (hi only); B = xs planes hi+lo.
// acc = A*(Bhi) + A*(Blo); dropped Alo*B term ~2^-12 relative, random sign.
// 128x128 tile, BK=32, 4 waves (2x2), split-K=2 via fp32 atomics.
__global__ __launch_bounds__(256) void kgemm(const unsigned short* __restrict__ Ahi,
                                             const unsigned short* __restrict__ Bhi,
                                             const unsigned short* __restrict__ Blo,
                                             float* __restrict__ pj){
    __shared__ unsigned short lds[3*4096];             // 24 KB, 3 linear planes
    unsigned short* Ah = lds;
    unsigned short* Bh = lds + 4096;
    unsigned short* Bl = lds + 8192;
    const int tid = threadIdx.x;
    const int z = blockIdx.z;
    const int h = z >> 1, ks = z & 1;
    const int k0 = blockIdx.x * 128;   // over C1
    const int c0 = blockIdx.y * 128;   // over C2
    const int lane = tid & 63, wid = tid >> 6;
    const int wr = wid >> 1, wc = wid & 1;
    const int lr = lane & 15, lk = (lane >> 4) * 8;

    f32x4 acc[4][4];
#pragma unroll
    for (int m = 0; m < 4; ++m)
#pragma unroll
        for (int nn = 0; nn < 4; ++nn) acc[m][nn] = (f32x4){0.f, 0.f, 0.f, 0.f};

    const size_t baseA = (size_t)(h*C2N + c0);
    const size_t baseB = (size_t)(h*C1N + k0);
    const int row0 = tid >> 2,          cu0 = (tid & 3) * 8;
    const int row1 = (256 + tid) >> 2,  cu1 = (tid & 3) * 8;
    const int lo0 = tid * 8, lo1 = (256 + tid) * 8;

    for (int t = 0; t < 2048/32; ++t){
        const int n0 = ks*2048 + t*32;
        {
            size_t gA0 = (baseA + row0)*NDIM + n0 + cu0;
            size_t gB0 = (baseB + row0)*NDIM + n0 + cu0;
            size_t gA1 = (baseA + row1)*NDIM + n0 + cu1;
            size_t gB1 = (baseB + row1)*NDIM + n0 + cu1;
            gl16(Ahi + gA0, Ah + lo0);
            gl16(Ahi + gA1, Ah + lo1);
            gl16(Bhi + gB0, Bh + lo0);
            gl16(Bhi + gB1, Bh + lo1);
            gl16(Blo + gB0, Bl + lo0);
            gl16(Blo + gB1, Bl + lo1);
        }
        __syncthreads();   // compiler drains vmcnt before s_barrier
        half8 ah[4];
#pragma unroll
        for (int m = 0; m < 4; ++m)
            ah[m] = *reinterpret_cast<const half8*>(&Ah[(wr*64 + m*16 + lr)*32 + lk]);
#pragma unroll
        for (int nn = 0; nn < 4; ++nn){
            half8 bh = *reinterpret_cast<const half8*>(&Bh[(wc*64 + nn*16 + lr)*32 + lk]);
            half8 bl = *reinterpret_cast<const half8*>(&Bl[(wc*64 + nn*16 + lr)*32 + lk]);
#pragma unroll
            for (int m = 0; m < 4; ++m){
                acc[m][nn] = __builtin_amdgcn_mfma_f32_16x16x32_f16(ah[m], bh, acc[m][nn], 0, 0, 0);
                acc[m][nn] = __builtin_amdgcn_mfma_f32_16x16x32_f16(ah[m], bl, acc[m][nn], 0, 0, 0);
            }
        }
        __syncthreads();
    }
    const int rr4 = (lane >> 4) * 4;
#pragma unroll
    for (int m = 0; m < 4; ++m)
#pragma unroll
        for (int nn = 0; nn < 4; ++nn)
#pragma unroll
            for (int r = 0; r < 4; ++r){
                int c = c0 + wr*64 + m*16 + rr4 + r;
                int k = k0 + wc*64 + nn*16 + lr;
                atomicAdd(&pj[((size_t)(h*C2N + c))*C1N + k], acc[m][nn][r]);
            }
}

// ---------------- final: sum pj*(log pj - log ps) ----------------
__global__ __launch_bounds__(256) void kfinal(const float* __restrict__ pj,
                                              const float* __restrict__ lps,
                                              float* S){
    float acc = 0.f;
    const int total = HN*C2N*C1N;
    const int stride = gridDim.x * 256;
    for (int i = blockIdx.x*256 + threadIdx.x; i < total; i += stride){
        float t = fmaxf(pj[i] * (1.f/NDIM), EPSV);
        int k = i & (C1N - 1);
        int h = i >> 21;
        acc += t * (logf(t) - lps[h*C1N + k]);
    }
    for (int o = 32; o > 0; o >>= 1) acc += __shfl_xor(acc, o);
    __shared__ float red[4];
    if ((threadIdx.x & 63) == 0) red[threadIdx.x >> 6] = acc;
    __syncthreads();
    if (threadIdx.x == 0) atomicAdd(&S[0], red[0]+red[1]+red[2]+red[3]);
}

__global__ void kfinish(const float* S, float* out){
    if (threadIdx.x == 0) out[0] = 0.25f * (S[1] - S[0]);
}

// ---------------- workspace layout (bytes) ----------------
#define XU_H16_OFF   0ull           // 4*2048*4096*2 = 67108864
#define XS_H16_OFF   67108864ull    // 33554432
#define XS_L16_OFF   100663296ull   // 33554432
#define PJ_OFF       134217728ull   // 33554432
#define STATS_S_OFF  167772160ull   // 131072
#define STATS_U_OFF  167903232ull   // 131072
#define PSUM_S_OFF   168034304ull   // 16384
#define PSUM_U_OFF   168050688ull   // 32768
#define LPS_OFF      168083456ull   // 16384
#define SACC_OFF     168099840ull   // 8

extern "C" void kernel_launch(void* const* d_in, const int* in_sizes, int n_in,
                              void* d_out, int out_size, void* d_ws, size_t ws_size,
                              hipStream_t stream){
    const float* x_seen   = (const float*)d_in[0];
    const float* x_unseen = (const float*)d_in[1];
    char* ws = (char*)d_ws;

    unsigned short* xu_h16 = (unsigned short*)(ws + XU_H16_OFF);
    unsigned short* xs_h16 = (unsigned short*)(ws + XS_H16_OFF);
    unsigned short* xs_l16 = (unsigned short*)(ws + XS_L16_OFF);
    float*  pj      = (float*)(ws + PJ_OFF);
    float2* stats_s = (float2*)(ws + STATS_S_OFF);
    float2* stats_u = (float2*)(ws + STATS_U_OFF);
    float*  psum_s  = (float*)(ws + PSUM_S_OFF);
    float*  psum_u  = (float*)(ws + PSUM_U_OFF);
    float*  lps     = (float*)(ws + LPS_OFF);
    float*  Sacc    = (float*)(ws + SACC_OFF);
    float*  out     = (float*)d_out;

    // zero pj + psum_s/psum_u/lps/Sacc (contiguous from PJ_OFF)
    const int nz = (int)((SACC_OFF + 8 - PJ_OFF) / 4);
    kzero<<<(nz + 255)/256, 256, 0, stream>>>(pj, nz);

    kstats<C1N><<<HN*NDIM, 256, 0, stream>>>(x_seen, stats_s);
    kstats<C2N><<<HN*NDIM, 256, 0, stream>>>(x_unseen, stats_u);

    knt<C1N, true ><<<dim3(C1N/64, NDIM/64, HN), 256, 0, stream>>>(x_seen, stats_s, xs_h16, xs_l16, psum_s);
    knt<C2N, false><<<dim3(C2N/64, NDIM/64, HN), 256, 0, stream>>>(x_unseen, stats_u, xu_h16, xu_h16, psum_u);

    kls<<<32, 256, 0, stream>>>(psum_s, psum_u, lps, Sacc);

    kgemm<<<dim3(C1N/128, C2N/128, HN*KSPLIT), 256, 0, stream>>>(xu_h16, xs_h16, xs_l16, pj);

    kfinal<<<2048, 256, 0, stream>>>(pj, lps, Sacc);
    kfinish<<<1, 64, 0, stream>>>(Sacc, out);
}

// Round 4
// 647.435 us; speedup vs baseline: 1.0370x; 1.0370x over previous
//
#include <hip/hip_runtime.h>
#include <hip/hip_fp16.h>

#define HN 4
#define VDIM 2
#define BDIM 2048
#define C1N 1024
#define C2N 2048
#define NDIM 4096
#define EPSV 1e-7f
#define ITEMP (1.0f/0.05f)
#define KSPLIT 2

typedef float f32x4 __attribute__((ext_vector_type(4)));
typedef _Float16 half8 __attribute__((ext_vector_type(8)));

// async global -> LDS, 16B per lane (m97 pattern; LDS dest linear in lane)
__device__ __forceinline__ void gl16(const void* g, void* l){
    __builtin_amdgcn_global_load_lds(
        (const __attribute__((address_space(1))) unsigned int*)g,
        (__attribute__((address_space(3))) unsigned int*)l, 16, 0, 0);
}

// ---------------- zero init (pj .. Sacc region) ----------------
__global__ void kzero(float* p, int n){
    int i = blockIdx.x * blockDim.x + threadIdx.x;
    if (i < n) p[i] = 0.f;
}

// ---------------- pass 1: row softmax stats (max, 1/sum) ----------------
template<int C>
__global__ __launch_bounds__(256) void kstats(const float* __restrict__ x,
                                              float2* __restrict__ st){
    const int bid = blockIdx.x;            // h*NDIM + n
    const int h = bid >> 12;
    const int n = bid & (NDIM - 1);
    const int v = n >> 11, b = n & (BDIM - 1);
    const float4* row = (const float4*)(x + ((size_t)((v*HN + h)*BDIM + b)) * C);
    const int t = threadIdx.x;
    constexpr int NV = C / 1024;
    float4 a[NV];
    float m = -3.4e38f;
#pragma unroll
    for (int i = 0; i < NV; ++i){
        a[i] = row[t + i*256];
        m = fmaxf(m, fmaxf(fmaxf(a[i].x, a[i].y), fmaxf(a[i].z, a[i].w)));
    }
    __shared__ float red[4];
    for (int o = 32; o > 0; o >>= 1) m = fmaxf(m, __shfl_xor(m, o));
    if ((t & 63) == 0) red[t >> 6] = m;
    __syncthreads();
    m = fmaxf(fmaxf(red[0], red[1]), fmaxf(red[2], red[3]));
    __syncthreads();
    float s = 0.f;
#pragma unroll
    for (int i = 0; i < NV; ++i){
        s += expf((a[i].x - m)*ITEMP) + expf((a[i].y - m)*ITEMP)
           + expf((a[i].z - m)*ITEMP) + expf((a[i].w - m)*ITEMP);
    }
    for (int o = 32; o > 0; o >>= 1) s += __shfl_xor(s, o);
    if ((t & 63) == 0) red[t >> 6] = s;
    __syncthreads();
    if (t == 0){
        float tot = red[0] + red[1] + red[2] + red[3];
        st[bid] = make_float2(m, 1.f / tot);
    }
}

// ---- pass 2: normalize + fp16 + transpose to (h,C,N) + exact fp32 colsum ----
template<int C>
__global__ __launch_bounds__(256) void knt(const float* __restrict__ x,
                                           const float2* __restrict__ st,
                                           unsigned short* __restrict__ thi,
                                           float* __restrict__ psum){
    __shared__ unsigned short sh[64][68];
    __shared__ float2 sst[64];
    const int tid = threadIdx.x;
    const int h  = blockIdx.z;
    const int c0 = blockIdx.x * 64;   // over C
    const int r0 = blockIdx.y * 64;   // over N
    if (tid < 64) sst[tid] = st[h*NDIM + r0 + tid];
    __syncthreads();
    const int col = (tid & 15) * 4;
    float csum[4] = {0.f, 0.f, 0.f, 0.f};
#pragma unroll
    for (int i = 0; i < 4; ++i){
        const int rr = (tid >> 4) + i*16;
        const int n = r0 + rr;
        const int v = n >> 11, b = n & (BDIM - 1);
        float4 xv = *(const float4*)(x + ((size_t)((v*HN + h)*BDIM + b))*C + c0 + col);
        const float m = sst[rr].x, inv = sst[rr].y;
        float vals[4] = {xv.x, xv.y, xv.z, xv.w};
#pragma unroll
        for (int e = 0; e < 4; ++e){
            float val = expf((vals[e] - m)*ITEMP) * inv;
            csum[e] += val;
            sh[rr][col + e] = __half_as_ushort(__float2half_rn(val));
        }
    }
    // exact fp32 column sums: lanes {l, l+16, l+32, l+48} share columns
#pragma unroll
    for (int e = 0; e < 4; ++e){
        csum[e] += __shfl_xor(csum[e], 16);
        csum[e] += __shfl_xor(csum[e], 32);
    }
    if ((tid & 63) < 16){
#pragma unroll
        for (int e = 0; e < 4; ++e)
            atomicAdd(&psum[h*C + c0 + col + e], csum[e]);
    }
    __syncthreads();
    const int rb = (tid & 15) * 4;
#pragma unroll
    for (int i = 0; i < 4; ++i){
        const int cc = (tid >> 4) + i*16;
        ushort4 vh;
        vh.x = sh[rb+0][cc]; vh.y = sh[rb+1][cc]; vh.z = sh[rb+2][cc]; vh.w = sh[rb+3][cc];
        size_t o = ((size_t)(h*C + c0 + cc))*NDIM + r0 + rb;
        *(ushort4*)(thi + o) = vh;
    }
}

// ---------------- merged: log(p_seen) table + p_unseen entropy ----------------
__global__ __launch_bounds__(256) void kls(const float* __restrict__ psum_s,
                                           const float* __restrict__ psum_u,
                                           float* __restrict__ lps, float* S){
    int i = blockIdx.x * 256 + threadIdx.x;
    if (i < HN*C1N) lps[i] = logf(fmaxf(psum_s[i] * (1.f/NDIM), EPSV));
    float t = 0.f;
    if (i < HN*C2N){
        float pu = fmaxf(psum_u[i] * (1.f/NDIM), EPSV);
        t = pu * logf(pu);
    }
    for (int o = 32; o > 0; o >>= 1) t += __shfl_xor(t, o);
    __shared__ float red[4];
    if ((threadIdx.x & 63) == 0) red[threadIdx.x >> 6] = t;
    __syncthreads();
    if (threadIdx.x == 0) atomicAdd(&S[1], red[0]+red[1]+red[2]+red[3]);
}

// ------ GEMM (m97 structure, single-fp16):
// pj[h][c][k] += sum_n xu[h][n][c]*xs[h][n][k]
// A = xu_h16 (h,C2,N) K-contig; B = xs_h16 (h,C1,N) K-contig.
// 128x128 tile, BK=32, 4 waves (2x2), split-K=2 via fp32 atomics. Linear LDS,
// global_load_lds width-16 staging, 2 barriers per K-step.
__global__ __launch_bounds__(256) void kgemm(const unsigned short* __restrict__ Ahi,
                                             const unsigned short* __restrict__ Bhi,
                                             float* __restrict__ pj){
    __shared__ unsigned short lds[2*4096];             // 16 KB, 2 linear planes
    unsigned short* Ah = lds;
    unsigned short* Bh = lds + 4096;
    const int tid = threadIdx.x;
    const int z = blockIdx.z;
    const int h = z >> 1, ks = z & 1;
    const int k0 = blockIdx.x * 128;   // over C1
    const int c0 = blockIdx.y * 128;   // over C2
    const int lane = tid & 63, wid = tid >> 6;
    const int wr = wid >> 1, wc = wid & 1;
    const int lr = lane & 15, lk = (lane >> 4) * 8;

    f32x4 acc[4][4];
#pragma unroll
    for (int m = 0; m < 4; ++m)
#pragma unroll
        for (int nn = 0; nn < 4; ++nn) acc[m][nn] = (f32x4){0.f, 0.f, 0.f, 0.f};

    const size_t baseA = (size_t)(h*C2N + c0);
    const size_t baseB = (size_t)(h*C1N + k0);
    const int row0 = tid >> 2,          cu0 = (tid & 3) * 8;
    const int row1 = (256 + tid) >> 2,  cu1 = (tid & 3) * 8;
    const int lo0 = tid * 8, lo1 = (256 + tid) * 8;

    for (int t = 0; t < 2048/32; ++t){
        const int n0 = ks*2048 + t*32;
        {
            size_t gA0 = (baseA + row0)*NDIM + n0 + cu0;
            size_t gB0 = (baseB + row0)*NDIM + n0 + cu0;
            size_t gA1 = (baseA + row1)*NDIM + n0 + cu1;
            size_t gB1 = (baseB + row1)*NDIM + n0 + cu1;
            gl16(Ahi + gA0, Ah + lo0);
            gl16(Ahi + gA1, Ah + lo1);
            gl16(Bhi + gB0, Bh + lo0);
            gl16(Bhi + gB1, Bh + lo1);
        }
        __syncthreads();   // compiler drains vmcnt before s_barrier
        half8 ah[4];
#pragma unroll
        for (int m = 0; m < 4; ++m)
            ah[m] = *reinterpret_cast<const half8*>(&Ah[(wr*64 + m*16 + lr)*32 + lk]);
#pragma unroll
        for (int nn = 0; nn < 4; ++nn){
            half8 bh = *reinterpret_cast<const half8*>(&Bh[(wc*64 + nn*16 + lr)*32 + lk]);
#pragma unroll
            for (int m = 0; m < 4; ++m)
                acc[m][nn] = __builtin_amdgcn_mfma_f32_16x16x32_f16(ah[m], bh, acc[m][nn], 0, 0, 0);
        }
        __syncthreads();
    }
    const int rr4 = (lane >> 4) * 4;
#pragma unroll
    for (int m = 0; m < 4; ++m)
#pragma unroll
        for (int nn = 0; nn < 4; ++nn)
#pragma unroll
            for (int r = 0; r < 4; ++r){
                int c = c0 + wr*64 + m*16 + rr4 + r;
                int k = k0 + wc*64 + nn*16 + lr;
                atomicAdd(&pj[((size_t)(h*C2N + c))*C1N + k], acc[m][nn][r]);
            }
}

// ---------------- final: sum pj*(log pj - log ps) ----------------
__global__ __launch_bounds__(256) void kfinal(const float* __restrict__ pj,
                                              const float* __restrict__ lps,
                                              float* S){
    float acc = 0.f;
    const int total = HN*C2N*C1N;
    const int stride = gridDim.x * 256;
    for (int i = blockIdx.x*256 + threadIdx.x; i < total; i += stride){
        float t = fmaxf(pj[i] * (1.f/NDIM), EPSV);
        int k = i & (C1N - 1);
        int h = i >> 21;
        acc += t * (logf(t) - lps[h*C1N + k]);
    }
    for (int o = 32; o > 0; o >>= 1) acc += __shfl_xor(acc, o);
    __shared__ float red[4];
    if ((threadIdx.x & 63) == 0) red[threadIdx.x >> 6] = acc;
    __syncthreads();
    if (threadIdx.x == 0) atomicAdd(&S[0], red[0]+red[1]+red[2]+red[3]);
}

__global__ void kfinish(const float* S, float* out){
    if (threadIdx.x == 0) out[0] = 0.25f * (S[1] - S[0]);
}

// ---------------- workspace layout (bytes) ----------------
#define XU_H16_OFF   0ull           // 67108864
#define XS_H16_OFF   67108864ull    // 33554432
#define PJ_OFF       100663296ull   // 33554432
#define STATS_S_OFF  134217728ull   // 131072
#define STATS_U_OFF  134348800ull   // 131072
#define PSUM_S_OFF   134479872ull   // 16384
#define PSUM_U_OFF   134496256ull   // 32768
#define LPS_OFF      134529024ull   // 16384
#define SACC_OFF     134545408ull   // 8

extern "C" void kernel_launch(void* const* d_in, const int* in_sizes, int n_in,
                              void* d_out, int out_size, void* d_ws, size_t ws_size,
                              hipStream_t stream){
    const float* x_seen   = (const float*)d_in[0];
    const float* x_unseen = (const float*)d_in[1];
    char* ws = (char*)d_ws;

    unsigned short* xu_h16 = (unsigned short*)(ws + XU_H16_OFF);
    unsigned short* xs_h16 = (unsigned short*)(ws + XS_H16_OFF);
    float*  pj      = (float*)(ws + PJ_OFF);
    float2* stats_s = (float2*)(ws + STATS_S_OFF);
    float2* stats_u = (float2*)(ws + STATS_U_OFF);
    float*  psum_s  = (float*)(ws + PSUM_S_OFF);
    float*  psum_u  = (float*)(ws + PSUM_U_OFF);
    float*  lps     = (float*)(ws + LPS_OFF);
    float*  Sacc    = (float*)(ws + SACC_OFF);
    float*  out     = (float*)d_out;

    // zero pj + psum_s/psum_u/lps/Sacc (contiguous from PJ_OFF)
    const int nz = (int)((SACC_OFF + 8 - PJ_OFF) / 4);
    kzero<<<(nz + 255)/256, 256, 0, stream>>>(pj, nz);

    kstats<C1N><<<HN*NDIM, 256, 0, stream>>>(x_seen, stats_s);
    kstats<C2N><<<HN*NDIM, 256, 0, stream>>>(x_unseen, stats_u);

    knt<C1N><<<dim3(C1N/64, NDIM/64, HN), 256, 0, stream>>>(x_seen, stats_s, xs_h16, psum_s);
    knt<C2N><<<dim3(C2N/64, NDIM/64, HN), 256, 0, stream>>>(x_unseen, stats_u, xu_h16, psum_u);

    kls<<<32, 256, 0, stream>>>(psum_s, psum_u, lps, Sacc);

    kgemm<<<dim3(C1N/128, C2N/128, HN*KSPLIT), 256, 0, stream>>>(xu_h16, xs_h16, pj);

    kfinal<<<2048, 256, 0, stream>>>(pj, lps, Sacc);
    kfinish<<<1, 64, 0, stream>>>(Sacc, out);
}

// Round 6
// 596.165 us; speedup vs baseline: 1.1262x; 1.0860x over previous
//
#include <hip/hip_runtime.h>
#include <hip/hip_fp16.h>

#define HN 4
#define VDIM 2
#define BDIM 2048
#define C1N 1024
#define C2N 2048
#define NDIM 4096
#define EPSV 1e-7f
#define ITEMP (1.0f/0.05f)
#define KSPLIT 2
#define PJ_STRIDE 8388608ull   // HN*C2N*C1N floats per split-K partial

typedef float f32x4 __attribute__((ext_vector_type(4)));
typedef _Float16 half8 __attribute__((ext_vector_type(8)));

// async global -> LDS, 16B per lane (LDS dest linear in lane)
__device__ __forceinline__ void gl16(const void* g, void* l){
    __builtin_amdgcn_global_load_lds(
        (const __attribute__((address_space(1))) unsigned int*)g,
        (__attribute__((address_space(3))) unsigned int*)l, 16, 0, 0);
}

// ---------------- zero init (psum/lps/Sacc only — tiny) ----------------
__global__ void kzero(float* p, int n){
    int i = blockIdx.x * blockDim.x + threadIdx.x;
    if (i < n) p[i] = 0.f;
}

// ---------------- pass 1: row softmax stats (max, 1/sum) ----------------
template<int C>
__global__ __launch_bounds__(256) void kstats(const float* __restrict__ x,
                                              float2* __restrict__ st){
    const int bid = blockIdx.x;            // h*NDIM + n
    const int h = bid >> 12;
    const int n = bid & (NDIM - 1);
    const int v = n >> 11, b = n & (BDIM - 1);
    const float4* row = (const float4*)(x + ((size_t)((v*HN + h)*BDIM + b)) * C);
    const int t = threadIdx.x;
    constexpr int NV = C / 1024;
    float4 a[NV];
    float m = -3.4e38f;
#pragma unroll
    for (int i = 0; i < NV; ++i){
        a[i] = row[t + i*256];
        m = fmaxf(m, fmaxf(fmaxf(a[i].x, a[i].y), fmaxf(a[i].z, a[i].w)));
    }
    __shared__ float red[4];
    for (int o = 32; o > 0; o >>= 1) m = fmaxf(m, __shfl_xor(m, o));
    if ((t & 63) == 0) red[t >> 6] = m;
    __syncthreads();
    m = fmaxf(fmaxf(red[0], red[1]), fmaxf(red[2], red[3]));
    __syncthreads();
    float s = 0.f;
#pragma unroll
    for (int i = 0; i < NV; ++i){
        s += expf((a[i].x - m)*ITEMP) + expf((a[i].y - m)*ITEMP)
           + expf((a[i].z - m)*ITEMP) + expf((a[i].w - m)*ITEMP);
    }
    for (int o = 32; o > 0; o >>= 1) s += __shfl_xor(s, o);
    if ((t & 63) == 0) red[t >> 6] = s;
    __syncthreads();
    if (t == 0){
        float tot = red[0] + red[1] + red[2] + red[3];
        st[bid] = make_float2(m, 1.f / tot);
    }
}

// ---- pass 2: normalize + fp16 + transpose to (h,C,N) + exact fp32 colsum ----
template<int C>
__global__ __launch_bounds__(256) void knt(const float* __restrict__ x,
                                           const float2* __restrict__ st,
                                           unsigned short* __restrict__ thi,
                                           float* __restrict__ psum){
    __shared__ unsigned short sh[64][68];
    __shared__ float2 sst[64];
    const int tid = threadIdx.x;
    const int h  = blockIdx.z;
    const int c0 = blockIdx.x * 64;   // over C
    const int r0 = blockIdx.y * 64;   // over N
    if (tid < 64) sst[tid] = st[h*NDIM + r0 + tid];
    __syncthreads();
    const int col = (tid & 15) * 4;
    float csum[4] = {0.f, 0.f, 0.f, 0.f};
#pragma unroll
    for (int i = 0; i < 4; ++i){
        const int rr = (tid >> 4) + i*16;
        const int n = r0 + rr;
        const int v = n >> 11, b = n & (BDIM - 1);
        float4 xv = *(const float4*)(x + ((size_t)((v*HN + h)*BDIM + b))*C + c0 + col);
        const float m = sst[rr].x, inv = sst[rr].y;
        float vals[4] = {xv.x, xv.y, xv.z, xv.w};
#pragma unroll
        for (int e = 0; e < 4; ++e){
            float val = expf((vals[e] - m)*ITEMP) * inv;
            csum[e] += val;
            sh[rr][col + e] = __half_as_ushort(__float2half_rn(val));
        }
    }
    // exact fp32 column sums: lanes {l, l+16, l+32, l+48} share columns
#pragma unroll
    for (int e = 0; e < 4; ++e){
        csum[e] += __shfl_xor(csum[e], 16);
        csum[e] += __shfl_xor(csum[e], 32);
    }
    if ((tid & 63) < 16){
#pragma unroll
        for (int e = 0; e < 4; ++e)
            atomicAdd(&psum[h*C + c0 + col + e], csum[e]);
    }
    __syncthreads();
    const int rb = (tid & 15) * 4;
#pragma unroll
    for (int i = 0; i < 4; ++i){
        const int cc = (tid >> 4) + i*16;
        ushort4 vh;
        vh.x = sh[rb+0][cc]; vh.y = sh[rb+1][cc]; vh.z = sh[rb+2][cc]; vh.w = sh[rb+3][cc];
        size_t o = ((size_t)(h*C + c0 + cc))*NDIM + r0 + rb;
        *(ushort4*)(thi + o) = vh;
    }
}

// ---------------- merged: log(p_seen) table + p_unseen entropy ----------------
__global__ __launch_bounds__(256) void kls(const float* __restrict__ psum_s,
                                           const float* __restrict__ psum_u,
                                           float* __restrict__ lps, float* S){
    int i = blockIdx.x * 256 + threadIdx.x;
    if (i < HN*C1N) lps[i] = logf(fmaxf(psum_s[i] * (1.f/NDIM), EPSV));
    float t = 0.f;
    if (i < HN*C2N){
        float pu = fmaxf(psum_u[i] * (1.f/NDIM), EPSV);
        t = pu * logf(pu);
    }
    for (int o = 32; o > 0; o >>= 1) t += __shfl_xor(t, o);
    __shared__ float red[4];
    if ((threadIdx.x & 63) == 0) red[threadIdx.x >> 6] = t;
    __syncthreads();
    if (threadIdx.x == 0) atomicAdd(&S[1], red[0]+red[1]+red[2]+red[3]);
}

// ------ GEMM, 2-phase double-buffered (T3-min recipe):
// pj_part[ks][h][c][k] = sum_{n in half ks} xu[h][n][c]*xs[h][n][k]
// A = xu_h16 (h,C2,N) K-contig; B = xs_h16 (h,C1,N) K-contig.
// 128x128 tile, BK=32, 4 waves (2x2). Two LDS buffers; next tile's
// global_load_lds issued BEFORE current tile's ds_read+MFMA; one barrier/iter
// (its vmcnt(0) drains loads that flew during the MFMAs).
// LDS stores linear; 16B XOR swizzle applied to GLOBAL source + LDS READ
// (same involution both sides): halves col ^= ((row&3)<<3). Cuts 8-way
// ds_read bank conflict to 4-way.
__global__ __launch_bounds__(256) void kgemm(const unsigned short* __restrict__ Ahi,
                                             const unsigned short* __restrict__ Bhi,
                                             float* __restrict__ pj){
    __shared__ unsigned short lds[4*4096];   // 32 KB: A0,B0,A1,B1 planes
    unsigned short* A0 = lds;
    unsigned short* B0 = lds + 4096;
    unsigned short* A1 = lds + 8192;
    unsigned short* B1 = lds + 12288;
    const int tid = threadIdx.x;
    const int z = blockIdx.z;
    const int h = z >> 1, ks = z & 1;
    const int k0 = blockIdx.x * 128;   // over C1
    const int c0 = blockIdx.y * 128;   // over C2
    const int lane = tid & 63, wid = tid >> 6;
    const int wr = wid >> 1, wc = wid & 1;
    const int lr = lane & 15, lk = (lane >> 4) * 8;

    f32x4 acc[4][4];
#pragma unroll
    for (int m = 0; m < 4; ++m)
#pragma unroll
        for (int nn = 0; nn < 4; ++nn) acc[m][nn] = (f32x4){0.f, 0.f, 0.f, 0.f};

    const size_t baseA = (size_t)(h*C2N + c0);
    const size_t baseB = (size_t)(h*C1N + k0);
    // staging: 512 chunks/plane of 16B; thread does chunks {tid, tid+256}
    const int row0 = tid >> 2,        row1 = (256 + tid) >> 2;
    // source col swizzle (halves): ((ci&3)*8) ^ ((row&3)<<3); (row1&3)==(row0&3)
    const int cus  = ((tid & 3) * 8) ^ ((row0 & 3) << 3);
    const int lo0 = tid * 8, lo1 = (256 + tid) * 8;
    const int kbase = ks * 2048;

#define STAGE(Ad, Bd, t) { \
        const int n0 = kbase + (t)*32; \
        size_t gA0 = (baseA + row0)*NDIM + n0 + cus; \
        size_t gB0 = (baseB + row0)*NDIM + n0 + cus; \
        size_t gA1 = (baseA + row1)*NDIM + n0 + cus; \
        size_t gB1 = (baseB + row1)*NDIM + n0 + cus; \
        gl16(Ahi + gA0, (Ad) + lo0); \
        gl16(Ahi + gA1, (Ad) + lo1); \
        gl16(Bhi + gB0, (Bd) + lo0); \
        gl16(Bhi + gB1, (Bd) + lo1); \
    }

    // swizzled read offset for fragment row r: r*32 + (lk ^ ((r&3)<<3));
    // r&3 == lr&3 (m*16, w*64 are multiples of 4)
    const int rsw = lk ^ ((lr & 3) << 3);

#define COMPUTE(As, Bs) { \
        half8 ah[4]; \
        _Pragma("unroll") \
        for (int m = 0; m < 4; ++m) \
            ah[m] = *reinterpret_cast<const half8*>(&(As)[(wr*64 + m*16 + lr)*32 + rsw]); \
        _Pragma("unroll") \
        for (int nn = 0; nn < 4; ++nn){ \
            half8 bh = *reinterpret_cast<const half8*>(&(Bs)[(wc*64 + nn*16 + lr)*32 + rsw]); \
            _Pragma("unroll") \
            for (int m = 0; m < 4; ++m) \
                acc[m][nn] = __builtin_amdgcn_mfma_f32_16x16x32_f16(ah[m], bh, acc[m][nn], 0, 0, 0); \
        } \
    }

    STAGE(A0, B0, 0);
    __syncthreads();                 // tile 0 landed
    for (int t = 0; t < 64; t += 2){
        if (t + 1 < 64) STAGE(A1, B1, t + 1);   // prefetch next while computing
        COMPUTE(A0, B0);
        __syncthreads();             // drains prefetch vmcnt + lgkm, flips buffers
        if (t + 2 < 64) STAGE(A0, B0, t + 2);
        COMPUTE(A1, B1);
        __syncthreads();
    }
#undef STAGE
#undef COMPUTE

    float* dst = pj + (size_t)ks * PJ_STRIDE;
    const int rr4 = (lane >> 4) * 4;
#pragma unroll
    for (int m = 0; m < 4; ++m)
#pragma unroll
        for (int nn = 0; nn < 4; ++nn)
#pragma unroll
            for (int r = 0; r < 4; ++r){
                int c = c0 + wr*64 + m*16 + rr4 + r;
                int k = k0 + wc*64 + nn*16 + lr;
                dst[((size_t)(h*C2N + c))*C1N + k] = acc[m][nn][r];
            }
}

// ---------------- final: sum (pj0+pj1)/N * (log pj - log ps) ----------------
__global__ __launch_bounds__(256) void kfinal(const float* __restrict__ pj,
                                              const float* __restrict__ lps,
                                              float* S){
    float acc = 0.f;
    const int total = HN*C2N*C1N;
    const int stride = gridDim.x * 256;
    for (int i = blockIdx.x*256 + threadIdx.x; i < total; i += stride){
        float t = fmaxf((pj[i] + pj[i + PJ_STRIDE]) * (1.f/NDIM), EPSV);
        int k = i & (C1N - 1);
        int h = i >> 21;
        acc += t * (logf(t) - lps[h*C1N + k]);
    }
    for (int o = 32; o > 0; o >>= 1) acc += __shfl_xor(acc, o);
    __shared__ float red[4];
    if ((threadIdx.x & 63) == 0) red[threadIdx.x >> 6] = acc;
    __syncthreads();
    if (threadIdx.x == 0) atomicAdd(&S[0], red[0]+red[1]+red[2]+red[3]);
}

__global__ void kfinish(const float* S, float* out){
    if (threadIdx.x == 0) out[0] = 0.25f * (S[1] - S[0]);
}

// ---------------- workspace layout (bytes) ----------------
#define XU_H16_OFF   0ull           // 67108864
#define XS_H16_OFF   67108864ull    // 33554432
#define PJ_OFF       100663296ull   // 2 x 33554432 (split-K partials)
#define STATS_S_OFF  167772160ull   // 131072
#define STATS_U_OFF  167903232ull   // 131072
#define PSUM_S_OFF   168034304ull   // 16384
#define PSUM_U_OFF   168050688ull   // 32768
#define LPS_OFF      168083456ull   // 16384
#define SACC_OFF     168099840ull   // 8

extern "C" void kernel_launch(void* const* d_in, const int* in_sizes, int n_in,
                              void* d_out, int out_size, void* d_ws, size_t ws_size,
                              hipStream_t stream){
    const float* x_seen   = (const float*)d_in[0];
    const float* x_unseen = (const float*)d_in[1];
    char* ws = (char*)d_ws;

    unsigned short* xu_h16 = (unsigned short*)(ws + XU_H16_OFF);
    unsigned short* xs_h16 = (unsigned short*)(ws + XS_H16_OFF);
    float*  pj      = (float*)(ws + PJ_OFF);
    float2* stats_s = (float2*)(ws + STATS_S_OFF);
    float2* stats_u = (float2*)(ws + STATS_U_OFF);
    float*  psum_s  = (float*)(ws + PSUM_S_OFF);
    float*  psum_u  = (float*)(ws + PSUM_U_OFF);
    float*  lps     = (float*)(ws + LPS_OFF);
    float*  Sacc    = (float*)(ws + SACC_OFF);
    float*  out     = (float*)d_out;

    // zero psum_s/psum_u/lps/Sacc only (pj is fully overwritten, no atomics)
    kzero<<<65, 256, 0, stream>>>(psum_s, 16386);

    kstats<C1N><<<HN*NDIM, 256, 0, stream>>>(x_seen, stats_s);
    kstats<C2N><<<HN*NDIM, 256, 0, stream>>>(x_unseen, stats_u);

    knt<C1N><<<dim3(C1N/64, NDIM/64, HN), 256, 0, stream>>>(x_seen, stats_s, xs_h16, psum_s);
    knt<C2N><<<dim3(C2N/64, NDIM/64, HN), 256, 0, stream>>>(x_unseen, stats_u, xu_h16, psum_u);

    kls<<<32, 256, 0, stream>>>(psum_s, psum_u, lps, Sacc);

    kgemm<<<dim3(C1N/128, C2N/128, HN*KSPLIT), 256, 0, stream>>>(xu_h16, xs_h16, pj);

    kfinal<<<2048, 256, 0, stream>>>(pj, lps, Sacc);
    kfinish<<<1, 64, 0, stream>>>(Sacc, out);
}

// Round 7
// 485.315 us; speedup vs baseline: 1.3834x; 1.2284x over previous
//
#include <hip/hip_runtime.h>
#include <hip/hip_fp16.h>

#define HN 4
#define VDIM 2
#define BDIM 2048
#define C1N 1024
#define C2N 2048
#define NDIM 4096
#define EPSV 1e-7f
#define ITEMP (1.0f/0.05f)
#define KSPLIT 2
#define PJ_STRIDE 8388608ull   // HN*C2N*C1N floats per split-K partial

typedef float f32x4 __attribute__((ext_vector_type(4)));
typedef _Float16 half8 __attribute__((ext_vector_type(8)));
typedef short short8v __attribute__((ext_vector_type(8)));

// async global -> LDS, 16B per lane (LDS dest linear in lane)
__device__ __forceinline__ void gl16(const void* g, void* l){
    __builtin_amdgcn_global_load_lds(
        (const __attribute__((address_space(1))) unsigned int*)g,
        (__attribute__((address_space(3))) unsigned int*)l, 16, 0, 0);
}

// ---------------- zero init (psum/lps/Sacc only — tiny) ----------------
__global__ void kzero(float* p, int n){
    int i = blockIdx.x * blockDim.x + threadIdx.x;
    if (i < n) p[i] = 0.f;
}

// ---- fused pass 1: row softmax stats + normalize from registers + fp16 pack,
//      output n-major (h, N, C) fully coalesced ----
template<int C>
__global__ __launch_bounds__(256) void kns(const float* __restrict__ x,
                                           unsigned short* __restrict__ y){
    const int bid = blockIdx.x;            // h*NDIM + n
    const int h = bid >> 12;
    const int n = bid & (NDIM - 1);
    const int v = n >> 11, b = n & (BDIM - 1);
    const float4* row = (const float4*)(x + ((size_t)((v*HN + h)*BDIM + b)) * C);
    const int t = threadIdx.x;
    constexpr int NV = C / 1024;
    float4 a[NV];
    float m = -3.4e38f;
#pragma unroll
    for (int i = 0; i < NV; ++i){
        a[i] = row[t + i*256];
        m = fmaxf(m, fmaxf(fmaxf(a[i].x, a[i].y), fmaxf(a[i].z, a[i].w)));
    }
    __shared__ float red[4];
    for (int o = 32; o > 0; o >>= 1) m = fmaxf(m, __shfl_xor(m, o));
    if ((t & 63) == 0) red[t >> 6] = m;
    __syncthreads();
    m = fmaxf(fmaxf(red[0], red[1]), fmaxf(red[2], red[3]));
    __syncthreads();
    float s = 0.f;
    float e[NV][4];
#pragma unroll
    for (int i = 0; i < NV; ++i){
        e[i][0] = expf((a[i].x - m)*ITEMP);
        e[i][1] = expf((a[i].y - m)*ITEMP);
        e[i][2] = expf((a[i].z - m)*ITEMP);
        e[i][3] = expf((a[i].w - m)*ITEMP);
        s += e[i][0] + e[i][1] + e[i][2] + e[i][3];
    }
    for (int o = 32; o > 0; o >>= 1) s += __shfl_xor(s, o);
    if ((t & 63) == 0) red[t >> 6] = s;
    __syncthreads();
    const float inv = 1.f / (red[0] + red[1] + red[2] + red[3]);
    unsigned short* yr = y + (size_t)(h*NDIM + n) * C;
#pragma unroll
    for (int i = 0; i < NV; ++i){
        ushort4 p;
        p.x = __half_as_ushort(__float2half_rn(e[i][0] * inv));
        p.y = __half_as_ushort(__float2half_rn(e[i][1] * inv));
        p.z = __half_as_ushort(__float2half_rn(e[i][2] * inv));
        p.w = __half_as_ushort(__float2half_rn(e[i][3] * inv));
        *(ushort4*)(yr + (size_t)(t + i*256) * 4) = p;
    }
}

// ---- pass 2: pure fp16 tiled transpose (h,N,C) -> (h,C,N) + fp32 colsum ----
// tile 128 n x 64 c; LDS [c][n ^ swz(c)], swz(c)=((c>>2)&7)<<3 (keeps 8-chunks,
// spreads u16 scatter-writes ~4-way). 16B reads + 16B stores on global.
template<int C>
__global__ __launch_bounds__(256) void ktr(const unsigned short* __restrict__ y,
                                           unsigned short* __restrict__ xt,
                                           float* __restrict__ psum){
    __shared__ unsigned short sm[64*128];   // 16 KB
    const int tid = threadIdx.x;
    const int h  = blockIdx.z;
    const int c0 = blockIdx.x * 64;    // over C
    const int r0 = blockIdx.y * 128;   // over N
    const int col = (tid & 15) * 4;
    const int rbase = tid >> 4;        // 0..15
    float csum[4] = {0.f, 0.f, 0.f, 0.f};
#pragma unroll
    for (int i = 0; i < 8; ++i){
        const int rr = rbase + i*16;
        ushort4 v4 = *(const ushort4*)(y + ((size_t)(h*NDIM + r0 + rr))*C + c0 + col);
        unsigned short vv[4] = {v4.x, v4.y, v4.z, v4.w};
#pragma unroll
        for (int ee = 0; ee < 4; ++ee){
            csum[ee] += __half2float(__ushort_as_half(vv[ee]));
            const int c = col + ee;
            const int sw = ((c >> 2) & 7) << 3;
            sm[c*128 + (rr ^ sw)] = vv[ee];
        }
    }
#pragma unroll
    for (int ee = 0; ee < 4; ++ee){
        csum[ee] += __shfl_xor(csum[ee], 16);
        csum[ee] += __shfl_xor(csum[ee], 32);
    }
    if ((tid & 63) < 16){
#pragma unroll
        for (int ee = 0; ee < 4; ++ee)
            atomicAdd(&psum[h*C + c0 + col + ee], csum[ee]);
    }
    __syncthreads();
#pragma unroll
    for (int j = 0; j < 4; ++j){
        const int q = tid + 256*j;
        const int c = q >> 4;            // 0..63
        const int nb = (q & 15) * 8;     // 0..120
        const int sw = ((c >> 2) & 7) << 3;
        short8v w = *(const short8v*)&sm[c*128 + (nb ^ sw)];
        *(short8v*)(xt + (size_t)(h*C + c0 + c)*NDIM + r0 + nb) = w;
    }
}

// ---------------- merged: log(p_seen) table + p_unseen entropy ----------------
__global__ __launch_bounds__(256) void kls(const float* __restrict__ psum_s,
                                           const float* __restrict__ psum_u,
                                           float* __restrict__ lps, float* S){
    int i = blockIdx.x * 256 + threadIdx.x;
    if (i < HN*C1N) lps[i] = logf(fmaxf(psum_s[i] * (1.f/NDIM), EPSV));
    float t = 0.f;
    if (i < HN*C2N){
        float pu = fmaxf(psum_u[i] * (1.f/NDIM), EPSV);
        t = pu * logf(pu);
    }
    for (int o = 32; o > 0; o >>= 1) t += __shfl_xor(t, o);
    __shared__ float red[4];
    if ((threadIdx.x & 63) == 0) red[threadIdx.x >> 6] = t;
    __syncthreads();
    if (threadIdx.x == 0) atomicAdd(&S[1], red[0]+red[1]+red[2]+red[3]);
}

// ------ GEMM, 2-phase double-buffered (unchanged from round 6) ------
__global__ __launch_bounds__(256) void kgemm(const unsigned short* __restrict__ Ahi,
                                             const unsigned short* __restrict__ Bhi,
                                             float* __restrict__ pj){
    __shared__ unsigned short lds[4*4096];   // 32 KB: A0,B0,A1,B1 planes
    unsigned short* A0 = lds;
    unsigned short* B0 = lds + 4096;
    unsigned short* A1 = lds + 8192;
    unsigned short* B1 = lds + 12288;
    const int tid = threadIdx.x;
    const int z = blockIdx.z;
    const int h = z >> 1, ks = z & 1;
    const int k0 = blockIdx.x * 128;   // over C1
    const int c0 = blockIdx.y * 128;   // over C2
    const int lane = tid & 63, wid = tid >> 6;
    const int wr = wid >> 1, wc = wid & 1;
    const int lr = lane & 15, lk = (lane >> 4) * 8;

    f32x4 acc[4][4];
#pragma unroll
    for (int m = 0; m < 4; ++m)
#pragma unroll
        for (int nn = 0; nn < 4; ++nn) acc[m][nn] = (f32x4){0.f, 0.f, 0.f, 0.f};

    const size_t baseA = (size_t)(h*C2N + c0);
    const size_t baseB = (size_t)(h*C1N + k0);
    const int row0 = tid >> 2,        row1 = (256 + tid) >> 2;
    const int cus  = ((tid & 3) * 8) ^ ((row0 & 3) << 3);
    const int lo0 = tid * 8, lo1 = (256 + tid) * 8;
    const int kbase = ks * 2048;

#define STAGE(Ad, Bd, t) { \
        const int n0 = kbase + (t)*32; \
        size_t gA0 = (baseA + row0)*NDIM + n0 + cus; \
        size_t gB0 = (baseB + row0)*NDIM + n0 + cus; \
        size_t gA1 = (baseA + row1)*NDIM + n0 + cus; \
        size_t gB1 = (baseB + row1)*NDIM + n0 + cus; \
        gl16(Ahi + gA0, (Ad) + lo0); \
        gl16(Ahi + gA1, (Ad) + lo1); \
        gl16(Bhi + gB0, (Bd) + lo0); \
        gl16(Bhi + gB1, (Bd) + lo1); \
    }

    const int rsw = lk ^ ((lr & 3) << 3);

#define COMPUTE(As, Bs) { \
        half8 ah[4]; \
        _Pragma("unroll") \
        for (int m = 0; m < 4; ++m) \
            ah[m] = *reinterpret_cast<const half8*>(&(As)[(wr*64 + m*16 + lr)*32 + rsw]); \
        _Pragma("unroll") \
        for (int nn = 0; nn < 4; ++nn){ \
            half8 bh = *reinterpret_cast<const half8*>(&(Bs)[(wc*64 + nn*16 + lr)*32 + rsw]); \
            _Pragma("unroll") \
            for (int m = 0; m < 4; ++m) \
                acc[m][nn] = __builtin_amdgcn_mfma_f32_16x16x32_f16(ah[m], bh, acc[m][nn], 0, 0, 0); \
        } \
    }

    STAGE(A0, B0, 0);
    __syncthreads();
    for (int t = 0; t < 64; t += 2){
        if (t + 1 < 64) STAGE(A1, B1, t + 1);
        COMPUTE(A0, B0);
        __syncthreads();
        if (t + 2 < 64) STAGE(A0, B0, t + 2);
        COMPUTE(A1, B1);
        __syncthreads();
    }
#undef STAGE
#undef COMPUTE

    float* dst = pj + (size_t)ks * PJ_STRIDE;
    const int rr4 = (lane >> 4) * 4;
#pragma unroll
    for (int m = 0; m < 4; ++m)
#pragma unroll
        for (int nn = 0; nn < 4; ++nn)
#pragma unroll
            for (int r = 0; r < 4; ++r){
                int c = c0 + wr*64 + m*16 + rr4 + r;
                int k = k0 + wc*64 + nn*16 + lr;
                dst[((size_t)(h*C2N + c))*C1N + k] = acc[m][nn][r];
            }
}

// ---------------- final: sum (pj0+pj1)/N * (log pj - log ps) ----------------
__global__ __launch_bounds__(256) void kfinal(const float* __restrict__ pj,
                                              const float* __restrict__ lps,
                                              float* S){
    float acc = 0.f;
    const int total = HN*C2N*C1N;
    const int stride = gridDim.x * 256;
    for (int i = blockIdx.x*256 + threadIdx.x; i < total; i += stride){
        float t = fmaxf((pj[i] + pj[i + PJ_STRIDE]) * (1.f/NDIM), EPSV);
        int k = i & (C1N - 1);
        int h = i >> 21;
        acc += t * (logf(t) - lps[h*C1N + k]);
    }
    for (int o = 32; o > 0; o >>= 1) acc += __shfl_xor(acc, o);
    __shared__ float red[4];
    if ((threadIdx.x & 63) == 0) red[threadIdx.x >> 6] = acc;
    __syncthreads();
    if (threadIdx.x == 0) atomicAdd(&S[0], red[0]+red[1]+red[2]+red[3]);
}

__global__ void kfinish(const float* S, float* out){
    if (threadIdx.x == 0) out[0] = 0.25f * (S[1] - S[0]);
}

// ---------------- workspace layout (bytes) ----------------
// xt_u (GEMM A, (h,C2,N) fp16): 67108864 @ 0
// xt_s (GEMM B, (h,C1,N) fp16): 33554432 @ 67108864
// y16_u (n-major fp16, dead after ktr_u): 67108864 @ 100663296
// y16_s: 33554432 @ 167772160
// pj (2 split-K partials, 67108864) ALIASES y16_u @ 100663296 (written by
//   kgemm after ktr_u has consumed y16_u — stream-ordered, safe)
#define XT_U_OFF    0ull
#define XT_S_OFF    67108864ull
#define Y16U_OFF    100663296ull
#define Y16S_OFF    167772160ull
#define PJ_OFF      100663296ull
#define PSUM_S_OFF  201326592ull
#define PSUM_U_OFF  201342976ull
#define LPS_OFF     201375744ull
#define SACC_OFF    201392128ull

extern "C" void kernel_launch(void* const* d_in, const int* in_sizes, int n_in,
                              void* d_out, int out_size, void* d_ws, size_t ws_size,
                              hipStream_t stream){
    const float* x_seen   = (const float*)d_in[0];
    const float* x_unseen = (const float*)d_in[1];
    char* ws = (char*)d_ws;

    unsigned short* xt_u  = (unsigned short*)(ws + XT_U_OFF);
    unsigned short* xt_s  = (unsigned short*)(ws + XT_S_OFF);
    unsigned short* y16_u = (unsigned short*)(ws + Y16U_OFF);
    unsigned short* y16_s = (unsigned short*)(ws + Y16S_OFF);
    float*  pj      = (float*)(ws + PJ_OFF);
    float*  psum_s  = (float*)(ws + PSUM_S_OFF);
    float*  psum_u  = (float*)(ws + PSUM_U_OFF);
    float*  lps     = (float*)(ws + LPS_OFF);
    float*  Sacc    = (float*)(ws + SACC_OFF);
    float*  out     = (float*)d_out;

    // zero psum_s/psum_u/lps/Sacc (contiguous: 4096+8192+4096+2 floats)
    kzero<<<65, 256, 0, stream>>>(psum_s, 16386);

    kns<C1N><<<HN*NDIM, 256, 0, stream>>>(x_seen,   y16_s);
    kns<C2N><<<HN*NDIM, 256, 0, stream>>>(x_unseen, y16_u);

    ktr<C1N><<<dim3(C1N/64, NDIM/128, HN), 256, 0, stream>>>(y16_s, xt_s, psum_s);
    ktr<C2N><<<dim3(C2N/64, NDIM/128, HN), 256, 0, stream>>>(y16_u, xt_u, psum_u);

    kls<<<32, 256, 0, stream>>>(psum_s, psum_u, lps, Sacc);

    kgemm<<<dim3(C1N/128, C2N/128, HN*KSPLIT), 256, 0, stream>>>(xt_u, xt_s, pj);

    kfinal<<<2048, 256, 0, stream>>>(pj, lps, Sacc);
    kfinish<<<1, 64, 0, stream>>>(Sacc, out);
}